// Round 8
// baseline (101.554 us; speedup 1.0000x reference)
//
#include <hip/hip_runtime.h>
#include <hip/hip_bf16.h>
#include <math.h>

// SlowROIPool: adaptive 7x7 max-pool over integer ROI crops.
// images [N=4,C=256,H=50,W=50] f32, rois [R=256,4] f32, roi_idx [R] i32.
// out [R,C,7,7] f32.
//
// Direct-gather, no LDS (R7 lesson: LDS pipe ~16 us was the bottleneck:
// 256 waves/CU x 27 ds-ops x 5.8 cyc).
// Wave = (roi, 4-channel group); lanes 0..48 <-> (i,j) output bins.
//  - 16 clamped in-bin tap offsets computed ONCE per lane (invariant over c).
//  - Per channel: 16 x global_load_dword with scalar plane base + precomputed
//    vector offset (zero per-load VALU), fully unrolled over 4 channels ->
//    64 independent loads, single latency exposure, ~4 L1 lines per inst.
//  - Lanes 49..63 mirror lane 48 (same addresses -> coalesced away), masked
//    at the store only: zero divergence in the load path.
// All indices clamped: no address can leave its buffer under poisoned inputs.

#define S 7
#define NN 4
#define NC 256
#define NH 50
#define NW 50
#define PLANE (NH * NW)   // 2500
#define CPW 4             // channels per wave

__global__ __launch_bounds__(256) void roipool_kernel(
    const float* __restrict__ images,
    const float* __restrict__ rois,
    const int* __restrict__ roi_idx,
    float* __restrict__ out,
    int out_size)
{
    const int t    = threadIdx.x;
    const int lane = t & 63;
    const int wv   = __builtin_amdgcn_readfirstlane(t >> 6);   // wave id, scalar
    const int grp  = blockIdx.x * 4 + wv;    // channel-group id, < 16384
    const int r    = grp >> 6;               // ROI (64 groups per ROI), scalar
    const int c0   = (grp & 63) * CPW;       // channel base, scalar

    // ---- box math: scalar (r uniform), clamped (identity on sane inputs) ----
    const float rx1 = rois[4 * r + 0];
    const float ry1 = rois[4 * r + 1];
    const float rx2 = rois[4 * r + 2];
    const float ry2 = rois[4 * r + 3];
    int x1 = (int)floorf(rx1 * (float)NW);
    int y1 = (int)floorf(ry1 * (float)NH);
    int x2 = (int)ceilf(rx2 * (float)NW);
    int y2 = (int)ceilf(ry2 * (float)NH);
    x1 = min(max(x1, 0), NW - 1);
    y1 = min(max(y1, 0), NH - 1);
    x2 = min(max(x2, x1 + 1), NW);
    y2 = min(max(y2, y1 + 1), NH);
    const int sw = x2 - x1;
    const int sh = y2 - y1;

    int n = roi_idx[r];
    n = min(max(n, 0), NN - 1);

    // ---- per-lane bin: lanes 49..63 clone lane 48 (coalesced away) ----
    const int l = min(lane, S * S - 1);
    const int i = l / S;
    const int j = l - i * S;
    const int hs = (i * sh) / S;
    const int he = ((i + 1) * sh + S - 1) / S;   // span <= 4 for sh <= 22
    const int ws = (j * sw) / S;
    const int we = ((j + 1) * sw + S - 1) / S;

    // 16 tap offsets within a plane, strictly in-bin (clamps only duplicate)
    int off[16];
#pragma unroll
    for (int a = 0; a < 4; ++a) {
        const int h = y1 + min(hs + a, he - 1);      // <= y2-1 <= 49
#pragma unroll
        for (int b = 0; b < 4; ++b) {
            const int w = x1 + min(ws + b, we - 1);  // <= x2-1 <= 49
            off[a * 4 + b] = h * NW + w;             // in [0, 2500)
        }
    }

    // ---- gather + reduce, 4 channels fully unrolled ----
    const float* __restrict__ pb = images + (size_t)(n * NC + c0) * PLANE;
    float res[CPW];
#pragma unroll
    for (int k = 0; k < CPW; ++k) {
        const float* __restrict__ bp = pb + k * PLANE;   // scalar base
        float v0 = bp[off[0]],  v1 = bp[off[1]],  v2 = bp[off[2]],  v3 = bp[off[3]];
        float v4 = bp[off[4]],  v5 = bp[off[5]],  v6 = bp[off[6]],  v7 = bp[off[7]];
        float v8 = bp[off[8]],  v9 = bp[off[9]],  va = bp[off[10]], vb = bp[off[11]];
        float vc = bp[off[12]], vd = bp[off[13]], ve = bp[off[14]], vf = bp[off[15]];
        float m01 = fmaxf(v0, v1), m23 = fmaxf(v2, v3);
        float m45 = fmaxf(v4, v5), m67 = fmaxf(v6, v7);
        float m89 = fmaxf(v8, v9), mab = fmaxf(va, vb);
        float mcd = fmaxf(vc, vd), mef = fmaxf(ve, vf);
        float q0 = fmaxf(m01, m23), q1 = fmaxf(m45, m67);
        float q2 = fmaxf(m89, mab), q3 = fmaxf(mcd, mef);
        res[k] = fmaxf(fmaxf(q0, q1), fmaxf(q2, q3));
    }

    // ---- stores: 49 contiguous floats per (channel) plane ----
    if (lane < S * S) {
#pragma unroll
        for (int k = 0; k < CPW; ++k) {
            const size_t oi = (size_t)(r * NC + c0 + k) * (S * S) + lane;
            if (oi < (size_t)out_size) out[oi] = res[k];
        }
    }
}

extern "C" void kernel_launch(void* const* d_in, const int* in_sizes, int n_in,
                              void* d_out, int out_size, void* d_ws, size_t ws_size,
                              hipStream_t stream) {
    const float* images  = (const float*)d_in[0];
    const float* rois    = (const float*)d_in[1];
    const int*   roi_idx = (const int*)d_in[2];
    float* out = (float*)d_out;

    const int planes = out_size / (S * S);          // 65536
    const int groups = planes / CPW;                // 16384
    const int blocks = groups / 4;                  // 4096 (4 waves per block)
    roipool_kernel<<<blocks, 256, 0, stream>>>(images, rois, roi_idx, out, out_size);
}

// Round 10
// 79.408 us; speedup vs baseline: 1.2789x; 1.2789x over previous
//
#include <hip/hip_runtime.h>
#include <hip/hip_bf16.h>
#include <math.h>

// SlowROIPool: adaptive 7x7 max-pool over integer ROI crops.
// images [N=4,C=256,H=50,W=50] f32, rois [R=256,4] f32, roi_idx [R] i32.
// out [R,C,7,7] f32.
//
// R9 bug (fixed): PITCH=24 < 32 made staging lanes wl>=24 spill into the
// parity-partner's row — same-address multi-lane ds_write race. PITCH must
// exceed 31 for the 2x32-lane staging layout; 33 also gives bank=(h+w)%32:
// writes exactly 2-way (free), reads well spread (PITCH=32 would 7-way).
//
// Structure (R7 + DS-instruction-count cuts):
//  - ONE WAVE stages TWO channel planes of one ROI (box math amortized 2x).
//  - Staging: 11 fixed branchless rounds x 2 planes, 22 batched global loads,
//    writes at const 66-dword deltas -> ds_write2_b32 merging.
//  - Compute: UNCLAMPED taps (hs+a, ws+b): 16 const-delta offsets (<= 102
//    dwords) off one vaddr -> 8x ds_read2_b32; validity (a<dh)&(b<dw) via
//    cndmask to -inf on the 4-SIMD VALU pipe, off the single shared DS pipe.
//  - NO __syncthreads: each wave reads only its own LDS region.
// All indices clamped; LDS accesses bounded (max 724 < 726 floats/plane):
// nothing can leave its buffer even under transiently-poisoned inputs.

#define S 7
#define NN 4
#define NC 256
#define NH 50
#define NW 50
#define PLANE (NH * NW)   // 2500
#define MAXD 22           // max crop dim (bw,bh <= 0.4 -> span <= 22)
#define PITCH 33          // MUST be > 31 (staging writes cols 0..31 per row)
#define PPW 2             // planes (channels) per wave
#define WPB 4             // waves per block
#define NINF (-__builtin_huge_valf())

__global__ __launch_bounds__(256) void roipool_kernel(
    const float* __restrict__ images,
    const float* __restrict__ rois,
    const int* __restrict__ roi_idx,
    float* __restrict__ out,
    int out_size)
{
    __shared__ float lds[WPB][PPW][MAXD * PITCH];   // 4*2*726*4B = 23.2 KB

    const int t    = threadIdx.x;
    const int wid  = t >> 6;
    const int lane = t & 63;
    const int pair = blockIdx.x * WPB + wid;               // plane-pair id
    int r  = __builtin_amdgcn_readfirstlane(pair >> 7);    // 128 pairs per ROI
    r = min(max(r, 0), 255);
    const int c0 = (pair & 127) * PPW;

    // ---- box math: scalar (r in SGPR), clamped (identity on sane inputs) ----
    const float rx1 = rois[4 * r + 0];
    const float ry1 = rois[4 * r + 1];
    const float rx2 = rois[4 * r + 2];
    const float ry2 = rois[4 * r + 3];
    int x1 = __builtin_amdgcn_readfirstlane((int)floorf(rx1 * (float)NW));
    int y1 = __builtin_amdgcn_readfirstlane((int)floorf(ry1 * (float)NH));
    int x2 = __builtin_amdgcn_readfirstlane((int)ceilf(rx2 * (float)NW));
    int y2 = __builtin_amdgcn_readfirstlane((int)ceilf(ry2 * (float)NH));
    x1 = min(max(x1, 0), NW - 1);
    y1 = min(max(y1, 0), NH - 1);
    x2 = min(max(x2, x1 + 1), NW);
    y2 = min(max(y2, y1 + 1), NH);
    const int sw = min(x2 - x1, MAXD);   // identity on real data
    const int sh = min(y2 - y1, MAXD);

    int n = __builtin_amdgcn_readfirstlane(roi_idx[r]);
    n = min(max(n, 0), NN - 1);

    // ---- staging: 2 rows x 32 cols per round, 11 fixed rounds, 2 planes ----
    const int wl  = lane & 31;           // col 0..31 (cols >= sw: dup, never read)
    const int rh  = lane >> 5;           // row parity
    const int wlc = min(wl, sw - 1);
    const float* __restrict__ gb =
        images + (size_t)(n * NC + c0) * PLANE + (y1 * NW + x1) + wlc;

    float v[PPW][11];
#pragma unroll
    for (int k = 0; k < PPW; ++k) {
#pragma unroll
        for (int q = 0; q < 11; ++q) {
            const int hc = min(2 * q + rh, sh - 1);     // rows >= sh: dup, never read
            v[k][q] = gb[(size_t)k * PLANE + hc * NW];  // 22 batched loads
        }
    }

#pragma unroll
    for (int k = 0; k < PPW; ++k) {
        float* __restrict__ L = &lds[wid][k][0];
        const int wb = rh * PITCH + wl;                 // < 66, within row pair
#pragma unroll
        for (int q = 0; q < 11; ++q) {
            L[wb + q * 2 * PITCH] = v[k][q];   // 66-dword deltas -> ds_write2_b32
        }
    }

    // ---- compute: lanes 0..48 -> (i,j); 8x ds_read2_b32 + VALU masks ----
    const int l  = min(lane, S * S - 1);
    const int i  = l / S;
    const int j  = l - i * S;
    const int hs = (i * sh) / S;
    const int he = ((i + 1) * sh + S - 1) / S;
    const int ws = (j * sw) / S;
    const int we = ((j + 1) * sw + S - 1) / S;
    const int dh = he - hs;              // [1,4] for sh <= 22
    const int dw = we - ws;
    const int vb = hs * PITCH + ws;      // <= 18*33+18=612; +102 <= 714 < 726

    float m[PPW];
#pragma unroll
    for (int k = 0; k < PPW; ++k) m[k] = NINF;

#pragma unroll
    for (int a = 0; a < 4; ++a) {
#pragma unroll
        for (int b = 0; b < 4; ++b) {
            const bool valid = (a < dh) & (b < dw);
#pragma unroll
            for (int k = 0; k < PPW; ++k) {
                const float x = lds[wid][k][vb + a * PITCH + b];  // const-delta
                m[k] = fmaxf(m[k], valid ? x : NINF);
            }
        }
    }

    // ---- stores: 49 contiguous floats per plane ----
    if (lane < S * S) {
#pragma unroll
        for (int k = 0; k < PPW; ++k) {
            const size_t oi = (size_t)(r * NC + c0 + k) * (S * S) + lane;
            if (oi < (size_t)out_size) out[oi] = m[k];
        }
    }
}

extern "C" void kernel_launch(void* const* d_in, const int* in_sizes, int n_in,
                              void* d_out, int out_size, void* d_ws, size_t ws_size,
                              hipStream_t stream) {
    const float* images  = (const float*)d_in[0];
    const float* rois    = (const float*)d_in[1];
    const int*   roi_idx = (const int*)d_in[2];
    float* out = (float*)d_out;

    const int planes = out_size / (S * S);          // 65536
    const int pairs  = (planes + PPW - 1) / PPW;    // 32768
    const int blocks = (pairs + WPB - 1) / WPB;     // 8192
    roipool_kernel<<<blocks, 256, 0, stream>>>(images, rois, roi_idx, out, out_size);
}